// Round 5
// baseline (79.662 us; speedup 1.0000x reference)
//
#include <hip/hip_runtime.h>
#include <hip/hip_bf16.h>

#define VOCAB 30522
#define BZ 32
#define SEQ 2048
#define D 768
#define P 16
#define PH_ID 1
#define NROWS (BZ * SEQ)                 // 65536
#define NKEYS (VOCAB + P)                // 30538 (emb rows + prompt rows)
#define NB ((NKEYS >> 4) + 1)            // 1909 buckets of 16 keys
#define RPB 16                           // output rows per gather block

typedef float f32x4 __attribute__((ext_vector_type(4)));

// Pass 1: per batch row, compute source key per position (id, or VOCAB+rank
// for placeholders) and histogram keys into NB buckets. Grid: BZ x 256.
__global__ void srcid_kernel(const int* __restrict__ ids,
                             int* __restrict__ srcid,
                             int* __restrict__ hist) {
    const int b = blockIdx.x;
    const int t = threadIdx.x;
    const int* row = ids + (size_t)b * SEQ;
    const int base = t * 8;

    int v[8], m[8], cnt = 0;
#pragma unroll
    for (int i = 0; i < 8; ++i) {
        v[i] = row[base + i];
        m[i] = (v[i] == PH_ID) ? 1 : 0;
        cnt += m[i];
    }
    const int lane = t & 63, wave = t >> 6;
    int incl = cnt;
#pragma unroll
    for (int off = 1; off < 64; off <<= 1) {
        int x = __shfl_up(incl, off, 64);
        if (lane >= off) incl += x;
    }
    __shared__ int wsum[4];
    if (lane == 63) wsum[wave] = incl;
    __syncthreads();
    int run = incl - cnt;                 // exclusive prefix: #PH before base
    for (int w = 0; w < wave; ++w) run += wsum[w];

    int* srow = srcid + (size_t)b * SEQ;
#pragma unroll
    for (int i = 0; i < 8; ++i) {
        int key;
        if (m[i]) {
            int r = run < (P - 1) ? run : (P - 1);
            key = VOCAB + r;
            ++run;
        } else {
            key = v[i];
        }
        srow[base + i] = key;
        atomicAdd(&hist[key >> 4], 1);
    }
}

// Pass 2: exclusive prefix sum over NB bucket counts. Single block, 256 thr.
__global__ void scan_kernel(int* __restrict__ hist) {
    const int t = threadIdx.x;
    int v[8], sum = 0;
#pragma unroll
    for (int i = 0; i < 8; ++i) {
        const int idx = t * 8 + i;
        v[i] = (idx < NB) ? hist[idx] : 0;
        sum += v[i];
    }
    const int lane = t & 63, wave = t >> 6;
    int incl = sum;
#pragma unroll
    for (int off = 1; off < 64; off <<= 1) {
        int x = __shfl_up(incl, off, 64);
        if (lane >= off) incl += x;
    }
    __shared__ int wsum[4];
    if (lane == 63) wsum[wave] = incl;
    __syncthreads();
    int run = incl - sum;
    for (int w = 0; w < wave; ++w) run += wsum[w];
#pragma unroll
    for (int i = 0; i < 8; ++i) {
        const int idx = t * 8 + i;
        if (idx < NB) { hist[idx] = run; run += v[i]; }
    }
}

// Pass 3: scatter row indices into bucket-sorted order. Grid: 256 x 256.
__global__ void scatter_kernel(const int* __restrict__ srcid,
                               int* __restrict__ hist,
                               int* __restrict__ sorted) {
    const int i = blockIdx.x * 256 + threadIdx.x;
    const int key = srcid[i];
    const int pos = atomicAdd(&hist[key >> 4], 1);
    sorted[pos] = i;
}

// Pass 4: gather in sorted-key order (reads get L2/L3 reuse); scattered but
// per-row-contiguous 3 KB writes stay coalesced. XCD-bijective chunk map:
// each XCD owns a contiguous sorted range. Grid: 4096 x 256.
__global__ __launch_bounds__(256) void gather_kernel(
        const int* __restrict__ srcid,
        const int* __restrict__ sorted,
        const float* __restrict__ emb,
        const float* __restrict__ prompt,
        float* __restrict__ out) {
    constexpr int NF4 = D / 4;                        // 192
    constexpr int ITERS = RPB * NF4 / 256;            // 12
    constexpr int NWG = NROWS / RPB;                  // 4096 (divisible by 8)

    const int bid = blockIdx.x;
    const int chunk = (bid & 7) * (NWG / 8) + (bid >> 3);
    const int g0 = chunk * RPB;
    const int t = threadIdx.x;

    __shared__ const f32x4* s_src[RPB];
    __shared__ f32x4* s_dst[RPB];
    if (t < RPB) {
        const int r = sorted[g0 + t];
        const int k = srcid[r];
        s_src[t] = (k >= VOCAB)
                       ? (const f32x4*)(prompt + (size_t)(k - VOCAB) * D)
                       : (const f32x4*)(emb + (size_t)k * D);
        s_dst[t] = (f32x4*)(out + (size_t)r * D);
    }
    __syncthreads();

    f32x4 v[ITERS];
    int rr[ITERS], cc[ITERS];
#pragma unroll
    for (int k = 0; k < ITERS; ++k) {
        const int f = k * 256 + t;
        rr[k] = f / NF4;
        cc[k] = f - rr[k] * NF4;
        v[k] = s_src[rr[k]][cc[k]];
    }
#pragma unroll
    for (int k = 0; k < ITERS; ++k) {
        __builtin_nontemporal_store(v[k], &s_dst[rr[k]][cc[k]]);
    }
}

extern "C" void kernel_launch(void* const* d_in, const int* in_sizes, int n_in,
                              void* d_out, int out_size, void* d_ws, size_t ws_size,
                              hipStream_t stream) {
    const int*   ids    = (const int*)d_in[0];     // [BZ, SEQ] int32
    const float* emb    = (const float*)d_in[1];   // [VOCAB, D] f32
    const float* prompt = (const float*)d_in[2];   // [P, D] f32
    float*       out    = (float*)d_out;           // [BZ, SEQ, D] f32

    int* hist   = (int*)d_ws;                      // NB ints
    int* srcid  = hist + NB;                       // NROWS ints
    int* sorted = srcid + NROWS;                   // NROWS ints  (~532 KB total)

    hipMemsetAsync(hist, 0, NB * sizeof(int), stream);
    srcid_kernel<<<BZ, 256, 0, stream>>>(ids, srcid, hist);
    scan_kernel<<<1, 256, 0, stream>>>(hist);
    scatter_kernel<<<NROWS / 256, 256, 0, stream>>>(srcid, hist, sorted);
    gather_kernel<<<NROWS / RPB, 256, 0, stream>>>(srcid, sorted, emb, prompt, out);
}